// Round 1
// baseline (1875.899 us; speedup 1.0000x reference)
//
#include <hip/hip_runtime.h>
#include <math.h>

#define NB 32768   // rows of x
#define KC 4096    // centroids
#define DD 512     // feature dim

// ---------------- kernel 1: c_sq[k] = sum_d c[k][d]^2 ----------------
__global__ __launch_bounds__(256) void csq_kernel(const float* __restrict__ cent,
                                                  float* __restrict__ csq) {
    const int wid  = threadIdx.x >> 6;
    const int lane = threadIdx.x & 63;
    const int k = (blockIdx.x << 2) + wid;          // grid = KC/4 blocks
    const float* row = cent + (size_t)k * DD;
    float s = 0.f;
#pragma unroll
    for (int d = 0; d < DD; d += 64) {
        float v = row[d + lane];
        s = fmaf(v, v, s);
    }
#pragma unroll
    for (int off = 32; off > 0; off >>= 1) s += __shfl_xor(s, off, 64);
    if (lane == 0) csq[k] = s;
}

// ---------------- kernel 2: fused GEMM + argmin ----------------
// tile: 64 rows x 128 cols, BK=16 depth staging, 256 threads.
// thread (tx,ty): rows m0 + ty*4 + i (i<4), cols n0 + h*64 + tx*4 + j (h<2, j<4)
__global__ __launch_bounds__(256) void argmin_kernel(const float* __restrict__ x,
                                                     const float* __restrict__ cent,
                                                     const float* __restrict__ csq,
                                                     int* __restrict__ out) {
    __shared__ float xs[16][68];    // [depth][row], pad 68: write groups 2-way (free)
    __shared__ float cs[16][132];   // [depth][col], pad 132

    const int tid = threadIdx.x;
    const int tx = tid & 15;
    const int ty = tid >> 4;
    const int m0 = blockIdx.x * 64;

    // staging: thread loads float4 of row srow at depth scol..scol+3
    const int srow = tid >> 2;          // 0..63
    const int scol = (tid & 3) << 2;    // 0,4,8,12

    const float* xg  = x    + (size_t)(m0 + srow) * DD + scol;
    const float* cgA = cent + (size_t)srow        * DD + scol;   // + n0*DD + k0
    const float* cgB = cent + (size_t)(srow + 64) * DD + scol;

    float best[4];
    int   bidx[4];
#pragma unroll
    for (int i = 0; i < 4; ++i) { best[i] = INFINITY; bidx[i] = 0; }

    for (int n0 = 0; n0 < KC; n0 += 128) {
        float acc[4][2][4];
#pragma unroll
        for (int i = 0; i < 4; ++i)
#pragma unroll
            for (int h = 0; h < 2; ++h)
#pragma unroll
                for (int j = 0; j < 4; ++j) acc[i][h][j] = 0.f;

        const size_t nOff = (size_t)n0 * DD;
        // prefetch k0 = 0
        float4 rx = *(const float4*)(xg);
        float4 rc0 = *(const float4*)(cgA + nOff);
        float4 rc1 = *(const float4*)(cgB + nOff);

        for (int k0 = 0; k0 < DD; k0 += 16) {
            __syncthreads();
            // transposed store into LDS
            {
                const float* p = (const float*)&rx;
                xs[scol + 0][srow] = p[0];
                xs[scol + 1][srow] = p[1];
                xs[scol + 2][srow] = p[2];
                xs[scol + 3][srow] = p[3];
                const float* q0 = (const float*)&rc0;
                cs[scol + 0][srow] = q0[0];
                cs[scol + 1][srow] = q0[1];
                cs[scol + 2][srow] = q0[2];
                cs[scol + 3][srow] = q0[3];
                const float* q1 = (const float*)&rc1;
                cs[scol + 0][srow + 64] = q1[0];
                cs[scol + 1][srow + 64] = q1[1];
                cs[scol + 2][srow + 64] = q1[2];
                cs[scol + 3][srow + 64] = q1[3];
            }
            __syncthreads();
            // prefetch next k-step (hides L2 latency under the FMA block)
            if (k0 + 16 < DD) {
                rx  = *(const float4*)(xg  + k0 + 16);
                rc0 = *(const float4*)(cgA + nOff + k0 + 16);
                rc1 = *(const float4*)(cgB + nOff + k0 + 16);
            }
#pragma unroll
            for (int dd = 0; dd < 16; ++dd) {
                float4 av  = *(const float4*)&xs[dd][ty << 2];
                float4 bv0 = *(const float4*)&cs[dd][tx << 2];
                float4 bv1 = *(const float4*)&cs[dd][64 + (tx << 2)];
                const float* a  = (const float*)&av;
                const float* b0 = (const float*)&bv0;
                const float* b1 = (const float*)&bv1;
#pragma unroll
                for (int i = 0; i < 4; ++i) {
#pragma unroll
                    for (int j = 0; j < 4; ++j) {
                        acc[i][0][j] = fmaf(a[i], b0[j], acc[i][0][j]);
                        acc[i][1][j] = fmaf(a[i], b1[j], acc[i][1][j]);
                    }
                }
            }
        }

        // fused argmin epilogue for this n-tile
        float4 qv0 = *(const float4*)(csq + n0 + (tx << 2));
        float4 qv1 = *(const float4*)(csq + n0 + 64 + (tx << 2));
        const float* q0 = (const float*)&qv0;
        const float* q1 = (const float*)&qv1;
#pragma unroll
        for (int i = 0; i < 4; ++i) {
#pragma unroll
            for (int h = 0; h < 2; ++h) {
#pragma unroll
                for (int j = 0; j < 4; ++j) {
                    float qq = (h == 0) ? q0[j] : q1[j];
                    float dist = fmaf(-2.f, acc[i][h][j], qq);
                    int kk = n0 + h * 64 + (tx << 2) + j;
                    if (dist < best[i] || (dist == best[i] && kk < bidx[i])) {
                        best[i] = dist; bidx[i] = kk;
                    }
                }
            }
        }
    }

    // reduce (min, first-idx) across the 16 tx lanes sharing each row set
#pragma unroll
    for (int off = 1; off < 16; off <<= 1) {
#pragma unroll
        for (int i = 0; i < 4; ++i) {
            float ov = __shfl_xor(best[i], off, 64);
            int   oi = __shfl_xor(bidx[i], off, 64);
            if (ov < best[i] || (ov == best[i] && oi < bidx[i])) {
                best[i] = ov; bidx[i] = oi;
            }
        }
    }
    if (tx == 0) {
#pragma unroll
        for (int i = 0; i < 4; ++i) out[m0 + (ty << 2) + i] = bidx[i];
    }
}

extern "C" void kernel_launch(void* const* d_in, const int* in_sizes, int n_in,
                              void* d_out, int out_size, void* d_ws, size_t ws_size,
                              hipStream_t stream) {
    const float* x    = (const float*)d_in[0];
    const float* cent = (const float*)d_in[1];
    int*   out = (int*)d_out;
    float* csq = (float*)d_ws;   // 4096 floats = 16 KB scratch

    csq_kernel<<<KC / 4, 256, 0, stream>>>(cent, csq);
    argmin_kernel<<<NB / 64, 256, 0, stream>>>(x, cent, csq, out);
}